// Round 2
// baseline (472.873 us; speedup 1.0000x reference)
//
#include <hip/hip_runtime.h>

#define NSAMP 400000
#define NBLK  1563   // ceil(400000/256)

// ---- workspace layout (bytes) ----
// 0    : double acc[43]  [0..3]=gsum [4..15]=gz [16..39]=gzz(sym) [40]=loss1sum [41]=energy_sum [42]=lossPart
// 352  : unsigned cnt    (last-block-done counter for fused final)
// 384  : float  P[10]    M00,M01,M02,M11,M12,M22, b0,b1,b2, A
// 1024 : float  G[256]   dec_w3 * dec_w3^T
// 2048 : float  g[16]    dec_w3 * dec_b3
// 2112 : float  bb[1]    ||dec_b3||^2
// 4096 : float4 zbuf[NSAMP]

__device__ __forceinline__ float ftanh(float x) {
    float e = __expf(2.0f * x);
    return 1.0f - __fdividef(2.0f, e + 1.0f);
}

__global__ __launch_bounds__(256) void prep_kernel(const float* __restrict__ dw3,
                                                   const float* __restrict__ db3,
                                                   float* __restrict__ Gm,
                                                   float* __restrict__ gv,
                                                   float* __restrict__ bb) {
    __shared__ float sw3[2048];   // 16 x 128
    __shared__ float sb3[128];
    int t = threadIdx.x;
    for (int k = t; k < 2048; k += 256) sw3[k] = dw3[k];
    if (t < 128) sb3[t] = db3[t];
    __syncthreads();
    int a = t >> 4, b = t & 15;
    float s = 0.f;
    for (int j = 0; j < 128; ++j) s = fmaf(sw3[a * 128 + j], sw3[b * 128 + j], s);
    Gm[t] = s;
    if (t < 16) {
        float sg = 0.f;
        for (int j = 0; j < 128; ++j) sg = fmaf(sw3[t * 128 + j], sb3[j], sg);
        gv[t] = sg;
    }
    if (t == 0) {
        float sbv = 0.f;
        for (int j = 0; j < 128; ++j) sbv = fmaf(sb3[j], sb3[j], sbv);
        *bb = sbv;
    }
}

__global__ __launch_bounds__(256) void pass1_kernel(
    const float* __restrict__ x1,
    const float* __restrict__ ew1, const float* __restrict__ eb1,
    const float* __restrict__ ew2, const float* __restrict__ eb2,
    const float* __restrict__ ew3, const float* __restrict__ eb3,
    const float* __restrict__ dw1, const float* __restrict__ db1,
    const float* __restrict__ dw2, const float* __restrict__ db2,
    const float* __restrict__ dw3, const float* __restrict__ db3,
    const float* __restrict__ tw1, const float* __restrict__ tb1,
    const float* __restrict__ tw2, const float* __restrict__ tb2,
    const float* __restrict__ Gm, const float* __restrict__ gv,
    const float* __restrict__ bbp,
    double* __restrict__ acc, float4* __restrict__ zbuf) {
    // LDS tile: 256 rows x 16 cols (one column-chunk), stored as float4 slots.
    // Slot (row, qs) holds global float4 column-group q = qs ^ ((row>>1)&3)
    // => per-thread ds_read_b128 of own row is bank-conflict-free.
    __shared__ float4 lbuf[1024];     // 16 KiB
    __shared__ float sPart[4][41];

    int t = threadIdx.x;
    int i = blockIdx.x * 256 + t;
    bool active = (i < NSAMP);
    int bbase = blockIdx.x * 256;
    int w = t >> 6, lane = t & 63;
    int sw2 = (t >> 1) & 3;
    const float4* x1f4 = (const float4*)x1;

    float u[16], v[16];
#pragma unroll
    for (int k = 0; k < 16; ++k) { u[k] = 0.f; v[k] = 0.f; }
    float s2 = 0.f, sb = 0.f;

#pragma unroll 1
    for (int blk = 0; blk < 8; ++blk) {
        // ---- stage chunk blk: coalesced global -> LDS (DMA, no VGPR round-trip)
#pragma unroll
        for (int c2 = 0; c2 < 4; ++c2) {
            int idx = (w * 4 + c2) * 64 + lane;      // 0..1023 slot index
            int row = idx >> 2, qs = idx & 3;
            int q = qs ^ ((row >> 1) & 3);
            int grow = bbase + row;
            if (grow >= NSAMP) grow = NSAMP - 1;     // clamp tail (results discarded)
            const float4* src = x1f4 + (size_t)grow * 32 + blk * 4 + q;
            float4* dst = lbuf + (w * 4 + c2) * 64;  // wave-uniform base; lane offset implicit
            __builtin_amdgcn_global_load_lds(
                (const __attribute__((address_space(1))) void*)src,
                (__attribute__((address_space(3))) void*)dst, 16, 0, 0);
        }
        __syncthreads();

        // ---- consume chunk blk from LDS (own row, swizzled slots)
        float xe[16];
#pragma unroll
        for (int q = 0; q < 4; ++q) {
            float4 w4 = lbuf[t * 4 + (q ^ sw2)];
            xe[q * 4 + 0] = w4.x; xe[q * 4 + 1] = w4.y;
            xe[q * 4 + 2] = w4.z; xe[q * 4 + 3] = w4.w;
        }
        int j0 = blk * 16;
#pragma unroll
        for (int e = 0; e < 16; ++e) {
            float x = xe[e];
            s2 = fmaf(x, x, s2);
            sb = fmaf(x, db3[j0 + e], sb);
#pragma unroll
            for (int k = 0; k < 16; ++k) u[k] = fmaf(x, ew1[(j0 + e) * 16 + k], u[k]);
        }
#pragma unroll
        for (int q = 0; q < 16; ++q) {
            float a2 = v[q];
#pragma unroll
            for (int e = 0; e < 16; ++e) a2 = fmaf(xe[e], dw3[q * 128 + j0 + e], a2);
            v[q] = a2;
        }
        __syncthreads();   // all waves done reading before next chunk's DMA lands
    }

    // encoder tail
    float h1[16];
#pragma unroll
    for (int k = 0; k < 16; ++k) h1[k] = ftanh(u[k] + eb1[k]);
    float h2[8];
#pragma unroll
    for (int m = 0; m < 8; ++m) {
        float a2 = eb2[m];
#pragma unroll
        for (int k = 0; k < 16; ++k) a2 = fmaf(h1[k], ew2[k * 8 + m], a2);
        h2[m] = ftanh(a2);
    }
    float a3 = eb3[0];
#pragma unroll
    for (int m = 0; m < 8; ++m) a3 = fmaf(h2[m], ew3[m], a3);
    float z1 = ftanh(a3);

    // decoder (x2 never materialized)
    float d1[8];
#pragma unroll
    for (int p = 0; p < 8; ++p) d1[p] = ftanh(fmaf(z1, dw1[p], db1[p]));
    float d2[16];
#pragma unroll
    for (int q = 0; q < 16; ++q) {
        float a2 = db2[q];
#pragma unroll
        for (int p = 0; p < 8; ++p) a2 = fmaf(d1[p], dw2[p * 16 + q], a2);
        d2[q] = ftanh(a2);
    }

    // distances via precomputed Gram
    float dot = sb;
#pragma unroll
    for (int q = 0; q < 16; ++q) dot = fmaf(d2[q], v[q], dot);
    float n2 = *bbp;
#pragma unroll
    for (int a = 0; a < 16; ++a) {
        float ra = 2.0f * gv[a];
#pragma unroll
        for (int b = 0; b < 16; ++b) ra = fmaf(Gm[a * 16 + b], d2[b], ra);
        n2 = fmaf(d2[a], ra, n2);
    }
    n2 = fmaxf(n2, 1e-20f);
    float euc2 = fmaxf(s2 - 2.0f * dot + n2, 0.f);
    float deuc = sqrtf(euc2);
    float dcos = dot * rsqrtf(s2 * n2);

    float zf[3] = {z1, dcos, deuc};

    // estimator
    float e1[8];
#pragma unroll
    for (int p = 0; p < 8; ++p) {
        float a2 = tb1[p];
        a2 = fmaf(zf[0], tw1[0 * 8 + p], a2);
        a2 = fmaf(zf[1], tw1[1 * 8 + p], a2);
        a2 = fmaf(zf[2], tw1[2 * 8 + p], a2);
        e1[p] = ftanh(a2);
    }
    float lg[4];
#pragma unroll
    for (int k = 0; k < 4; ++k) {
        float a2 = tb2[k];
#pragma unroll
        for (int p = 0; p < 8; ++p) a2 = fmaf(e1[p], tw2[p * 4 + k], a2);
        lg[k] = a2;
    }
    float mx = fmaxf(fmaxf(lg[0], lg[1]), fmaxf(lg[2], lg[3]));
    float ex[4]; float se = 0.f;
#pragma unroll
    for (int k = 0; k < 4; ++k) { ex[k] = __expf(lg[k] - mx); se += ex[k]; }
    float inv = __fdividef(1.0f, se);
    float gam[4];
#pragma unroll
    for (int k = 0; k < 4; ++k) gam[k] = ex[k] * inv;

    if (active) zbuf[i] = make_float4(zf[0], zf[1], zf[2], 0.f);
    if (!active) { gam[0] = gam[1] = gam[2] = gam[3] = 0.f; euc2 = 0.f; }

    // block reduction of 41 moment values
    int rlane = threadIdx.x & 63;
    int wid = threadIdx.x >> 6;

#define REDUCE_STORE(T, VAL) { float _v = (VAL);                          \
        _v += __shfl_down(_v, 32); _v += __shfl_down(_v, 16);             \
        _v += __shfl_down(_v, 8);  _v += __shfl_down(_v, 4);              \
        _v += __shfl_down(_v, 2);  _v += __shfl_down(_v, 1);              \
        if (rlane == 0) sPart[wid][T] = _v; }

#pragma unroll
    for (int k = 0; k < 4; ++k) REDUCE_STORE(k, gam[k]);
#pragma unroll
    for (int k = 0; k < 4; ++k) {
#pragma unroll
        for (int d = 0; d < 3; ++d) REDUCE_STORE(4 + k * 3 + d, gam[k] * zf[d]);
    }
#pragma unroll
    for (int k = 0; k < 4; ++k) {
        REDUCE_STORE(16 + k * 6 + 0, gam[k] * zf[0] * zf[0]);
        REDUCE_STORE(16 + k * 6 + 1, gam[k] * zf[0] * zf[1]);
        REDUCE_STORE(16 + k * 6 + 2, gam[k] * zf[0] * zf[2]);
        REDUCE_STORE(16 + k * 6 + 3, gam[k] * zf[1] * zf[1]);
        REDUCE_STORE(16 + k * 6 + 4, gam[k] * zf[1] * zf[2]);
        REDUCE_STORE(16 + k * 6 + 5, gam[k] * zf[2] * zf[2]);
    }
    REDUCE_STORE(40, euc2);
#undef REDUCE_STORE

    __syncthreads();
    if (threadIdx.x < 41) {
        double s = (double)sPart[0][threadIdx.x] + (double)sPart[1][threadIdx.x]
                 + (double)sPart[2][threadIdx.x] + (double)sPart[3][threadIdx.x];
        unsafeAtomicAdd(&acc[threadIdx.x], s);
    }
}

__global__ void gmm_kernel(double* __restrict__ acc, float* __restrict__ P) {
    if (threadIdx.x != 0 || blockIdx.x != 0) return;
    double M[6] = {0, 0, 0, 0, 0, 0}, bv[3] = {0, 0, 0}, A = 0.0, loss3 = 0.0;
    const double TWO_PI = 6.283185307179586;
    for (int k = 0; k < 4; ++k) {
        double g = acc[k];
        double phi = g / (double)NSAMP;
        double mu0 = acc[4 + k * 3 + 0] / g;
        double mu1 = acc[4 + k * 3 + 1] / g;
        double mu2 = acc[4 + k * 3 + 2] / g;
        double S00 = acc[16 + k * 6 + 0] / g - mu0 * mu0;
        double S01 = acc[16 + k * 6 + 1] / g - mu0 * mu1;
        double S02 = acc[16 + k * 6 + 2] / g - mu0 * mu2;
        double S11 = acc[16 + k * 6 + 3] / g - mu1 * mu1;
        double S12 = acc[16 + k * 6 + 4] / g - mu1 * mu2;
        double S22 = acc[16 + k * 6 + 5] / g - mu2 * mu2;
        double c00 = S11 * S22 - S12 * S12;
        double c01 = S02 * S12 - S01 * S22;
        double c02 = S01 * S12 - S02 * S11;
        double det = S00 * c00 + S01 * c01 + S02 * c02;
        double id = 1.0 / det;
        double I00 = c00 * id, I01 = c01 * id, I02 = c02 * id;
        double I11 = (S00 * S22 - S02 * S02) * id;
        double I12 = (S01 * S02 - S00 * S12) * id;
        double I22 = (S00 * S11 - S01 * S01) * id;
        M[0] += I00; M[1] += I01; M[2] += I02; M[3] += I11; M[4] += I12; M[5] += I22;
        double b0 = I00 * mu0 + I01 * mu1 + I02 * mu2;
        double b1 = I01 * mu0 + I11 * mu1 + I12 * mu2;
        double b2 = I02 * mu0 + I12 * mu1 + I22 * mu2;
        bv[0] += b0; bv[1] += b1; bv[2] += b2;
        double quad = mu0 * b0 + mu1 * b1 + mu2 * b2;
        A += -log(phi) + 0.5 * log(TWO_PI * TWO_PI * TWO_PI * det) + 0.5 * quad;
        loss3 += 1e-4 * (1.0 / S00 + 1.0 / S11 + 1.0 / S22);
    }
    P[0] = (float)M[0]; P[1] = (float)M[1]; P[2] = (float)M[2];
    P[3] = (float)M[3]; P[4] = (float)M[4]; P[5] = (float)M[5];
    P[6] = (float)bv[0]; P[7] = (float)bv[1]; P[8] = (float)bv[2];
    P[9] = (float)A;
    acc[42] = acc[40] / (double)NSAMP + loss3;   // loss1 + loss3
}

__global__ __launch_bounds__(256) void energy_kernel(const float4* __restrict__ zbuf,
                                                     const float* __restrict__ P,
                                                     double* __restrict__ acc,
                                                     unsigned* __restrict__ cnt,
                                                     float* __restrict__ out) {
    int i = blockIdx.x * 256 + threadIdx.x;
    float e = 0.f;
    if (i < NSAMP) {
        float4 z4 = zbuf[i];
        float z0 = z4.x, z1 = z4.y, z2 = z4.z;
        float q = P[0] * z0 * z0 + P[3] * z1 * z1 + P[5] * z2 * z2
                + 2.f * (P[1] * z0 * z1 + P[2] * z0 * z2 + P[4] * z1 * z2);
        e = P[9] + 0.5f * q - (P[6] * z0 + P[7] * z1 + P[8] * z2);
        out[i] = e;
    }
    float s = e;
    s += __shfl_down(s, 32); s += __shfl_down(s, 16); s += __shfl_down(s, 8);
    s += __shfl_down(s, 4);  s += __shfl_down(s, 2);  s += __shfl_down(s, 1);
    __shared__ float sE[4];
    if ((threadIdx.x & 63) == 0) sE[threadIdx.x >> 6] = s;
    __syncthreads();
    if (threadIdx.x == 0) {
        double t = (double)sE[0] + (double)sE[1] + (double)sE[2] + (double)sE[3];
        unsafeAtomicAdd(&acc[41], t);
        __threadfence();
        unsigned old = atomicAdd(cnt, 1u);
        if (old == (unsigned)(NBLK - 1)) {
            // last block: all energy partials visible (fence-before-count on every block)
            double tot = unsafeAtomicAdd(&acc[41], 0.0);  // atomic read, bypasses L1
            out[NSAMP] = (float)(acc[42] + 0.01 * tot / (double)NSAMP);
        }
    }
}

extern "C" void kernel_launch(void* const* d_in, const int* in_sizes, int n_in,
                              void* d_out, int out_size, void* d_ws, size_t ws_size,
                              hipStream_t stream) {
    const float* x1  = (const float*)d_in[0];
    const float* ew1 = (const float*)d_in[1];
    const float* eb1 = (const float*)d_in[2];
    const float* ew2 = (const float*)d_in[3];
    const float* eb2 = (const float*)d_in[4];
    const float* ew3 = (const float*)d_in[5];
    const float* eb3 = (const float*)d_in[6];
    const float* dw1 = (const float*)d_in[7];
    const float* db1 = (const float*)d_in[8];
    const float* dw2 = (const float*)d_in[9];
    const float* db2 = (const float*)d_in[10];
    const float* dw3 = (const float*)d_in[11];
    const float* db3 = (const float*)d_in[12];
    const float* tw1 = (const float*)d_in[13];
    const float* tb1 = (const float*)d_in[14];
    const float* tw2 = (const float*)d_in[15];
    const float* tb2 = (const float*)d_in[16];
    float* out = (float*)d_out;
    char* ws = (char*)d_ws;
    double* acc   = (double*)ws;
    unsigned* cnt = (unsigned*)(ws + 352);
    float* P    = (float*)(ws + 384);
    float* Gm   = (float*)(ws + 1024);
    float* gv   = (float*)(ws + 2048);
    float* bb   = (float*)(ws + 2112);
    float4* zb  = (float4*)(ws + 4096);

    hipMemsetAsync(d_ws, 0, 512, stream);
    prep_kernel<<<1, 256, 0, stream>>>(dw3, db3, Gm, gv, bb);
    pass1_kernel<<<NBLK, 256, 0, stream>>>(x1, ew1, eb1, ew2, eb2, ew3, eb3,
                                           dw1, db1, dw2, db2, dw3, db3,
                                           tw1, tb1, tw2, tb2, Gm, gv, bb, acc, zb);
    gmm_kernel<<<1, 64, 0, stream>>>(acc, P);
    energy_kernel<<<NBLK, 256, 0, stream>>>(zb, P, acc, cnt, out);
}

// Round 4
// 471.300 us; speedup vs baseline: 1.0033x; 1.0033x over previous
//
#include <hip/hip_runtime.h>

#define NSAMP 400000
#define NBLK  1563   // ceil(400000/256)

// ---- workspace layout (bytes) ----
// 0    : double acc[43]  [0..3]=gsum [4..15]=gz [16..39]=gzz(sym) [40]=loss1sum [41]=energy_sum [42]=lossPart
// 352  : unsigned cnt    (last-block-done counter for fused final)
// 384  : float  P[10]    M00,M01,M02,M11,M12,M22, b0,b1,b2, A
// 1024 : float  G[256]   dec_w3 * dec_w3^T
// 2048 : float  g[16]    dec_w3 * dec_b3
// 2112 : float  bb[1]    ||dec_b3||^2
// 4096 : float4 zbuf[NSAMP]

__device__ __forceinline__ float ftanh(float x) {
    float e = __expf(2.0f * x);
    return 1.0f - __fdividef(2.0f, e + 1.0f);
}

__global__ __launch_bounds__(256) void prep_kernel(const float* __restrict__ dw3,
                                                   const float* __restrict__ db3,
                                                   float* __restrict__ Gm,
                                                   float* __restrict__ gv,
                                                   float* __restrict__ bb) {
    __shared__ float sw3[2048];   // 16 x 128
    __shared__ float sb3[128];
    int t = threadIdx.x;
    for (int k = t; k < 2048; k += 256) sw3[k] = dw3[k];
    if (t < 128) sb3[t] = db3[t];
    __syncthreads();
    int a = t >> 4, b = t & 15;
    float s = 0.f;
    for (int j = 0; j < 128; ++j) s = fmaf(sw3[a * 128 + j], sw3[b * 128 + j], s);
    Gm[t] = s;
    if (t < 16) {
        float sg = 0.f;
        for (int j = 0; j < 128; ++j) sg = fmaf(sw3[t * 128 + j], sb3[j], sg);
        gv[t] = sg;
    }
    if (t == 0) {
        float sbv = 0.f;
        for (int j = 0; j < 128; ++j) sbv = fmaf(sb3[j], sb3[j], sbv);
        *bb = sbv;
    }
}

__global__ __launch_bounds__(256) void pass1_kernel(
    const float* __restrict__ x1,
    const float* __restrict__ ew1, const float* __restrict__ eb1,
    const float* __restrict__ ew2, const float* __restrict__ eb2,
    const float* __restrict__ ew3, const float* __restrict__ eb3,
    const float* __restrict__ dw1, const float* __restrict__ db1,
    const float* __restrict__ dw2, const float* __restrict__ db2,
    const float* __restrict__ dw3, const float* __restrict__ db3,
    const float* __restrict__ tw1, const float* __restrict__ tb1,
    const float* __restrict__ tw2, const float* __restrict__ tb2,
    const float* __restrict__ Gm, const float* __restrict__ gv,
    const float* __restrict__ bbp,
    double* __restrict__ acc, float4* __restrict__ zbuf) {
    // Double-buffered LDS tile: 2 x (256 rows x 16 cols) as float4 slots.
    // Staging is WAVE-PRIVATE: wave w DMAs rows w*64..w*64+63, which only
    // wave w consumes => no __syncthreads in the chunk loop. RAW is enforced
    // per-wave via counted s_waitcnt vmcnt(4) (chunk k drained, chunk k+1's
    // 4 loads stay in flight under the consume phase). WAR is program order.
    // Slot (row, qs) holds global float4 column-group q = qs ^ ((row>>1)&3)
    // => per-thread ds_read_b128 of own row spreads banks.
    __shared__ float4 lbuf[2048];     // 32 KiB (2 buffers)
    __shared__ float sPart[4][41];

    int t = threadIdx.x;
    int i = blockIdx.x * 256 + t;
    bool active = (i < NSAMP);
    int bbase = blockIdx.x * 256;
    int w = t >> 6, lane = t & 63;
    int sw2 = (t >> 1) & 3;
    const float4* x1f4 = (const float4*)x1;

    // per-thread DMA source pointers (affine in chunk: advance 4 float4/chunk)
    const float4* p[4];
#pragma unroll
    for (int c2 = 0; c2 < 4; ++c2) {
        int idx = (w * 4 + c2) * 64 + lane;      // 0..1023 slot index
        int row = idx >> 2, qs = idx & 3;
        int q = qs ^ ((row >> 1) & 3);
        int grow = bbase + row;
        if (grow >= NSAMP) grow = NSAMP - 1;     // clamp tail (results discarded)
        p[c2] = x1f4 + (size_t)grow * 32 + q;
    }

    // prologue: stage chunk 0 into buffer 0
#pragma unroll
    for (int c2 = 0; c2 < 4; ++c2) {
        __builtin_amdgcn_global_load_lds(
            (const __attribute__((address_space(1))) void*)p[c2],
            (__attribute__((address_space(3))) void*)(lbuf + (w * 4 + c2) * 64),
            16, 0, 0);
        p[c2] += 4;
    }

    float u[16], v[16];
#pragma unroll
    for (int k = 0; k < 16; ++k) { u[k] = 0.f; v[k] = 0.f; }
    float s2 = 0.f, sb = 0.f;

    auto consume = [&](int blk, int bofs) {
        float xe[16];
#pragma unroll
        for (int q = 0; q < 4; ++q) {
            float4 w4 = lbuf[bofs + t * 4 + (q ^ sw2)];
            xe[q * 4 + 0] = w4.x; xe[q * 4 + 1] = w4.y;
            xe[q * 4 + 2] = w4.z; xe[q * 4 + 3] = w4.w;
        }
        int j0 = blk * 16;
#pragma unroll
        for (int e = 0; e < 16; ++e) {
            float x = xe[e];
            s2 = fmaf(x, x, s2);
            sb = fmaf(x, db3[j0 + e], sb);
#pragma unroll
            for (int k = 0; k < 16; ++k) u[k] = fmaf(x, ew1[(j0 + e) * 16 + k], u[k]);
        }
#pragma unroll
        for (int q = 0; q < 16; ++q) {
            float a2 = v[q];
#pragma unroll
            for (int e = 0; e < 16; ++e) a2 = fmaf(xe[e], dw3[q * 128 + j0 + e], a2);
            v[q] = a2;
        }
    };

#pragma unroll 1
    for (int blk = 0; blk < 7; ++blk) {
        int nb = ((blk + 1) & 1) * 1024;
        // stage chunk blk+1 into the other buffer (wave-private region)
#pragma unroll
        for (int c2 = 0; c2 < 4; ++c2) {
            __builtin_amdgcn_global_load_lds(
                (const __attribute__((address_space(1))) void*)p[c2],
                (__attribute__((address_space(3))) void*)(lbuf + nb + (w * 4 + c2) * 64),
                16, 0, 0);
            p[c2] += 4;
        }
        // drain chunk blk's 4 DMAs, leave chunk blk+1's 4 in flight
        asm volatile("s_waitcnt vmcnt(4)" ::: "memory");
        __builtin_amdgcn_sched_barrier(0);
        consume(blk, (blk & 1) * 1024);
    }
    asm volatile("s_waitcnt vmcnt(0)" ::: "memory");
    __builtin_amdgcn_sched_barrier(0);
    consume(7, 1024);

    // encoder tail
    float h1[16];
#pragma unroll
    for (int k = 0; k < 16; ++k) h1[k] = ftanh(u[k] + eb1[k]);
    float h2[8];
#pragma unroll
    for (int m = 0; m < 8; ++m) {
        float a2 = eb2[m];
#pragma unroll
        for (int k = 0; k < 16; ++k) a2 = fmaf(h1[k], ew2[k * 8 + m], a2);
        h2[m] = ftanh(a2);
    }
    float a3 = eb3[0];
#pragma unroll
    for (int m = 0; m < 8; ++m) a3 = fmaf(h2[m], ew3[m], a3);
    float z1 = ftanh(a3);

    // decoder (x2 never materialized)
    float d1[8];
#pragma unroll
    for (int p2 = 0; p2 < 8; ++p2) d1[p2] = ftanh(fmaf(z1, dw1[p2], db1[p2]));
    float d2[16];
#pragma unroll
    for (int q = 0; q < 16; ++q) {
        float a2 = db2[q];
#pragma unroll
        for (int p2 = 0; p2 < 8; ++p2) a2 = fmaf(d1[p2], dw2[p2 * 16 + q], a2);
        d2[q] = ftanh(a2);
    }

    // distances via precomputed Gram
    float dot = sb;
#pragma unroll
    for (int q = 0; q < 16; ++q) dot = fmaf(d2[q], v[q], dot);
    float n2 = *bbp;
#pragma unroll
    for (int a = 0; a < 16; ++a) {
        float ra = 2.0f * gv[a];
#pragma unroll
        for (int b = 0; b < 16; ++b) ra = fmaf(Gm[a * 16 + b], d2[b], ra);
        n2 = fmaf(d2[a], ra, n2);
    }
    n2 = fmaxf(n2, 1e-20f);
    float euc2 = fmaxf(s2 - 2.0f * dot + n2, 0.f);
    float deuc = sqrtf(euc2);
    float dcos = dot * rsqrtf(s2 * n2);

    float zf[3] = {z1, dcos, deuc};

    // estimator
    float e1[8];
#pragma unroll
    for (int p2 = 0; p2 < 8; ++p2) {
        float a2 = tb1[p2];
        a2 = fmaf(zf[0], tw1[0 * 8 + p2], a2);
        a2 = fmaf(zf[1], tw1[1 * 8 + p2], a2);
        a2 = fmaf(zf[2], tw1[2 * 8 + p2], a2);
        e1[p2] = ftanh(a2);
    }
    float lg[4];
#pragma unroll
    for (int k = 0; k < 4; ++k) {
        float a2 = tb2[k];
#pragma unroll
        for (int p2 = 0; p2 < 8; ++p2) a2 = fmaf(e1[p2], tw2[p2 * 4 + k], a2);
        lg[k] = a2;
    }
    float mx = fmaxf(fmaxf(lg[0], lg[1]), fmaxf(lg[2], lg[3]));
    float ex[4]; float se = 0.f;
#pragma unroll
    for (int k = 0; k < 4; ++k) { ex[k] = __expf(lg[k] - mx); se += ex[k]; }
    float inv = __fdividef(1.0f, se);
    float gam[4];
#pragma unroll
    for (int k = 0; k < 4; ++k) gam[k] = ex[k] * inv;

    if (active) zbuf[i] = make_float4(zf[0], zf[1], zf[2], 0.f);
    if (!active) { gam[0] = gam[1] = gam[2] = gam[3] = 0.f; euc2 = 0.f; }

    // block reduction of 41 moment values
    int rlane = threadIdx.x & 63;
    int wid = threadIdx.x >> 6;

#define REDUCE_STORE(T, VAL) { float _v = (VAL);                          \
        _v += __shfl_down(_v, 32); _v += __shfl_down(_v, 16);             \
        _v += __shfl_down(_v, 8);  _v += __shfl_down(_v, 4);              \
        _v += __shfl_down(_v, 2);  _v += __shfl_down(_v, 1);              \
        if (rlane == 0) sPart[wid][T] = _v; }

#pragma unroll
    for (int k = 0; k < 4; ++k) REDUCE_STORE(k, gam[k]);
#pragma unroll
    for (int k = 0; k < 4; ++k) {
#pragma unroll
        for (int d = 0; d < 3; ++d) REDUCE_STORE(4 + k * 3 + d, gam[k] * zf[d]);
    }
#pragma unroll
    for (int k = 0; k < 4; ++k) {
        REDUCE_STORE(16 + k * 6 + 0, gam[k] * zf[0] * zf[0]);
        REDUCE_STORE(16 + k * 6 + 1, gam[k] * zf[0] * zf[1]);
        REDUCE_STORE(16 + k * 6 + 2, gam[k] * zf[0] * zf[2]);
        REDUCE_STORE(16 + k * 6 + 3, gam[k] * zf[1] * zf[1]);
        REDUCE_STORE(16 + k * 6 + 4, gam[k] * zf[1] * zf[2]);
        REDUCE_STORE(16 + k * 6 + 5, gam[k] * zf[2] * zf[2]);
    }
    REDUCE_STORE(40, euc2);
#undef REDUCE_STORE

    __syncthreads();
    if (threadIdx.x < 41) {
        double s = (double)sPart[0][threadIdx.x] + (double)sPart[1][threadIdx.x]
                 + (double)sPart[2][threadIdx.x] + (double)sPart[3][threadIdx.x];
        unsafeAtomicAdd(&acc[threadIdx.x], s);
    }
}

__global__ void gmm_kernel(double* __restrict__ acc, float* __restrict__ P) {
    if (threadIdx.x != 0 || blockIdx.x != 0) return;
    double M[6] = {0, 0, 0, 0, 0, 0}, bv[3] = {0, 0, 0}, A = 0.0, loss3 = 0.0;
    const double TWO_PI = 6.283185307179586;
    for (int k = 0; k < 4; ++k) {
        double g = acc[k];
        double phi = g / (double)NSAMP;
        double mu0 = acc[4 + k * 3 + 0] / g;
        double mu1 = acc[4 + k * 3 + 1] / g;
        double mu2 = acc[4 + k * 3 + 2] / g;
        double S00 = acc[16 + k * 6 + 0] / g - mu0 * mu0;
        double S01 = acc[16 + k * 6 + 1] / g - mu0 * mu1;
        double S02 = acc[16 + k * 6 + 2] / g - mu0 * mu2;
        double S11 = acc[16 + k * 6 + 3] / g - mu1 * mu1;
        double S12 = acc[16 + k * 6 + 4] / g - mu1 * mu2;
        double S22 = acc[16 + k * 6 + 5] / g - mu2 * mu2;
        double c00 = S11 * S22 - S12 * S12;
        double c01 = S02 * S12 - S01 * S22;
        double c02 = S01 * S12 - S02 * S11;
        double det = S00 * c00 + S01 * c01 + S02 * c02;
        double id = 1.0 / det;
        double I00 = c00 * id, I01 = c01 * id, I02 = c02 * id;
        double I11 = (S00 * S22 - S02 * S02) * id;
        double I12 = (S01 * S02 - S00 * S12) * id;
        double I22 = (S00 * S11 - S01 * S01) * id;
        M[0] += I00; M[1] += I01; M[2] += I02; M[3] += I11; M[4] += I12; M[5] += I22;
        double b0 = I00 * mu0 + I01 * mu1 + I02 * mu2;
        double b1 = I01 * mu0 + I11 * mu1 + I12 * mu2;
        double b2 = I02 * mu0 + I12 * mu1 + I22 * mu2;
        bv[0] += b0; bv[1] += b1; bv[2] += b2;
        double quad = mu0 * b0 + mu1 * b1 + mu2 * b2;
        A += -log(phi) + 0.5 * log(TWO_PI * TWO_PI * TWO_PI * det) + 0.5 * quad;
        loss3 += 1e-4 * (1.0 / S00 + 1.0 / S11 + 1.0 / S22);
    }
    P[0] = (float)M[0]; P[1] = (float)M[1]; P[2] = (float)M[2];
    P[3] = (float)M[3]; P[4] = (float)M[4]; P[5] = (float)M[5];
    P[6] = (float)bv[0]; P[7] = (float)bv[1]; P[8] = (float)bv[2];
    P[9] = (float)A;
    acc[42] = acc[40] / (double)NSAMP + loss3;   // loss1 + loss3
}

__global__ __launch_bounds__(256) void energy_kernel(const float4* __restrict__ zbuf,
                                                     const float* __restrict__ P,
                                                     double* __restrict__ acc,
                                                     unsigned* __restrict__ cnt,
                                                     float* __restrict__ out) {
    int i = blockIdx.x * 256 + threadIdx.x;
    float e = 0.f;
    if (i < NSAMP) {
        float4 z4 = zbuf[i];
        float z0 = z4.x, z1 = z4.y, z2 = z4.z;
        float q = P[0] * z0 * z0 + P[3] * z1 * z1 + P[5] * z2 * z2
                + 2.f * (P[1] * z0 * z1 + P[2] * z0 * z2 + P[4] * z1 * z2);
        e = P[9] + 0.5f * q - (P[6] * z0 + P[7] * z1 + P[8] * z2);
        out[i] = e;
    }
    float s = e;
    s += __shfl_down(s, 32); s += __shfl_down(s, 16); s += __shfl_down(s, 8);
    s += __shfl_down(s, 4);  s += __shfl_down(s, 2);  s += __shfl_down(s, 1);
    __shared__ float sE[4];
    if ((threadIdx.x & 63) == 0) sE[threadIdx.x >> 6] = s;
    __syncthreads();
    if (threadIdx.x == 0) {
        double t = (double)sE[0] + (double)sE[1] + (double)sE[2] + (double)sE[3];
        unsafeAtomicAdd(&acc[41], t);
        __threadfence();
        unsigned old = atomicAdd(cnt, 1u);
        if (old == (unsigned)(NBLK - 1)) {
            // last block: all energy partials visible (fence-before-count on every block)
            double tot = unsafeAtomicAdd(&acc[41], 0.0);  // atomic read, bypasses L1
            out[NSAMP] = (float)(acc[42] + 0.01 * tot / (double)NSAMP);
        }
    }
}

extern "C" void kernel_launch(void* const* d_in, const int* in_sizes, int n_in,
                              void* d_out, int out_size, void* d_ws, size_t ws_size,
                              hipStream_t stream) {
    const float* x1  = (const float*)d_in[0];
    const float* ew1 = (const float*)d_in[1];
    const float* eb1 = (const float*)d_in[2];
    const float* ew2 = (const float*)d_in[3];
    const float* eb2 = (const float*)d_in[4];
    const float* ew3 = (const float*)d_in[5];
    const float* eb3 = (const float*)d_in[6];
    const float* dw1 = (const float*)d_in[7];
    const float* db1 = (const float*)d_in[8];
    const float* dw2 = (const float*)d_in[9];
    const float* db2 = (const float*)d_in[10];
    const float* dw3 = (const float*)d_in[11];
    const float* db3 = (const float*)d_in[12];
    const float* tw1 = (const float*)d_in[13];
    const float* tb1 = (const float*)d_in[14];
    const float* tw2 = (const float*)d_in[15];
    const float* tb2 = (const float*)d_in[16];
    float* out = (float*)d_out;
    char* ws = (char*)d_ws;
    double* acc   = (double*)ws;
    unsigned* cnt = (unsigned*)(ws + 352);
    float* P    = (float*)(ws + 384);
    float* Gm   = (float*)(ws + 1024);
    float* gv   = (float*)(ws + 2048);
    float* bb   = (float*)(ws + 2112);
    float4* zb  = (float4*)(ws + 4096);

    hipMemsetAsync(d_ws, 0, 512, stream);
    prep_kernel<<<1, 256, 0, stream>>>(dw3, db3, Gm, gv, bb);
    pass1_kernel<<<NBLK, 256, 0, stream>>>(x1, ew1, eb1, ew2, eb2, ew3, eb3,
                                           dw1, db1, dw2, db2, dw3, db3,
                                           tw1, tb1, tw2, tb2, Gm, gv, bb, acc, zb);
    gmm_kernel<<<1, 64, 0, stream>>>(acc, P);
    energy_kernel<<<NBLK, 256, 0, stream>>>(zb, P, acc, cnt, out);
}

// Round 5
// 456.720 us; speedup vs baseline: 1.0354x; 1.0319x over previous
//
#include <hip/hip_runtime.h>

#define NSAMP 400000
#define NBLK  1563   // ceil(400000/256)

// ---- workspace layout (bytes) ----
// 0    : double acc[8][48]  8 contention-spread copies; [0..3]=gsum [4..15]=gz
//        [16..39]=gzz [40]=loss1sum [41]=energy_sum [42]=lossPart (copy0 only)
// 3072 : unsigned cnt
// 3584 : float  P[10]
// 4096 : float  Gm[256]
// 5120 : float  gv[16]
// 5184 : float  bb[1]
// 8192 : float4 zbuf[NSAMP]

__device__ __forceinline__ float ftanh(float x) {
    float e = __expf(2.0f * x);
    return 1.0f - __fdividef(2.0f, e + 1.0f);
}

__global__ __launch_bounds__(256) void prep_kernel(const float* __restrict__ dw3,
                                                   const float* __restrict__ db3,
                                                   float* __restrict__ Gm,
                                                   float* __restrict__ gv,
                                                   float* __restrict__ bb) {
    __shared__ float sw3[2048];   // 16 x 128
    __shared__ float sb3[128];
    int t = threadIdx.x;
    for (int k = t; k < 2048; k += 256) sw3[k] = dw3[k];
    if (t < 128) sb3[t] = db3[t];
    __syncthreads();
    int a = t >> 4, b = t & 15;
    float s = 0.f;
    for (int j = 0; j < 128; ++j) s = fmaf(sw3[a * 128 + j], sw3[b * 128 + j], s);
    Gm[t] = s;
    if (t < 16) {
        float sg = 0.f;
        for (int j = 0; j < 128; ++j) sg = fmaf(sw3[t * 128 + j], sb3[j], sg);
        gv[t] = sg;
    }
    if (t == 0) {
        float sbv = 0.f;
        for (int j = 0; j < 128; ++j) sbv = fmaf(sb3[j], sb3[j], sbv);
        *bb = sbv;
    }
}

__global__ __launch_bounds__(256) void pass1_kernel(
    const float* __restrict__ x1,
    const float* __restrict__ ew1, const float* __restrict__ eb1,
    const float* __restrict__ ew2, const float* __restrict__ eb2,
    const float* __restrict__ ew3, const float* __restrict__ eb3,
    const float* __restrict__ dw1, const float* __restrict__ db1,
    const float* __restrict__ dw2, const float* __restrict__ db2,
    const float* __restrict__ dw3, const float* __restrict__ db3,
    const float* __restrict__ tw1, const float* __restrict__ tb1,
    const float* __restrict__ tw2, const float* __restrict__ tb2,
    const float* __restrict__ Gm, const float* __restrict__ gv,
    const float* __restrict__ bbp,
    double* __restrict__ acc, float4* __restrict__ zbuf) {
    // x1 staging: double-buffered wave-private DMA (proven structure, R4).
    // NEW: ALL weights resident in LDS (loaded once per block, coalesced),
    // consumed as wave-uniform float4 ds_reads (broadcast, conflict-free).
    // This removes the per-chunk 2KB weight refetch that all prior variants
    // shared — the hypothesized latency bottleneck.
    __shared__ float4 lbuf[2048];     // 32 KiB x1 double buffer
    __shared__ float sPart[4][41];
    __shared__ __align__(16) float sEw1[2048];   // [j][k] 128x16
    __shared__ __align__(16) float sDw3[2048];   // [q][j] 16x128
    __shared__ __align__(16) float sGm[256];
    __shared__ __align__(16) float sDb3[128];
    __shared__ __align__(16) float sEw2[128];    // [k][m] 16x8
    __shared__ __align__(16) float sDw2[128];    // [p][q] 8x16
    __shared__ __align__(16) float sTw1[24];     // [d][p] 3x8
    __shared__ __align__(16) float sTw2[32];     // [p][k] 8x4
    __shared__ float sGv[16], sEb1[16], sDb2[16];
    __shared__ float sEb2[8], sEw3[8], sDw1[8], sDb1[8], sTb1[8];
    __shared__ float sTb2[4];
    __shared__ float sBb, sEb3;

    int t = threadIdx.x;
    int i = blockIdx.x * 256 + t;
    bool active = (i < NSAMP);
    int bbase = blockIdx.x * 256;
    int w = t >> 6, lane = t & 63;
    int sw2 = (t >> 1) & 3;
    const float4* x1f4 = (const float4*)x1;

    // per-thread DMA source pointers (affine in chunk)
    const float4* p[4];
#pragma unroll
    for (int c2 = 0; c2 < 4; ++c2) {
        int idx = (w * 4 + c2) * 64 + lane;
        int row = idx >> 2, qs = idx & 3;
        int q = qs ^ ((row >> 1) & 3);
        int grow = bbase + row;
        if (grow >= NSAMP) grow = NSAMP - 1;
        p[c2] = x1f4 + (size_t)grow * 32 + q;
    }
    // prologue: stage chunk 0 into buffer 0 (lands via the barrier below)
#pragma unroll
    for (int c2 = 0; c2 < 4; ++c2) {
        __builtin_amdgcn_global_load_lds(
            (const __attribute__((address_space(1))) void*)p[c2],
            (__attribute__((address_space(3))) void*)(lbuf + (w * 4 + c2) * 64),
            16, 0, 0);
        p[c2] += 4;
    }

    // cooperative weight preload (coalesced per-lane loads)
    for (int k = t; k < 2048; k += 256) { sEw1[k] = ew1[k]; sDw3[k] = dw3[k]; }
    sGm[t & 255] = Gm[t & 255];   // t<256 always
    if (t < 128) { sDb3[t] = db3[t]; sEw2[t] = ew2[t]; sDw2[t] = dw2[t]; }
    if (t < 16) { sGv[t] = gv[t]; sEb1[t] = eb1[t]; sDb2[t] = db2[t]; }
    if (t < 8) { sEb2[t] = eb2[t]; sEw3[t] = ew3[t]; sDw1[t] = dw1[t];
                 sDb1[t] = db1[t]; sTb1[t] = tb1[t]; }
    if (t < 24) sTw1[t] = tw1[t];
    if (t < 32) sTw2[t] = tw2[t];
    if (t < 4) sTb2[t] = tb2[t];
    if (t == 0) { sBb = *bbp; sEb3 = eb3[0]; }
    __syncthreads();   // weights visible; also drains chunk-0 DMA (vmcnt 0 here)

    const float4* sEw1_4 = (const float4*)sEw1;
    const float4* sDw3_4 = (const float4*)sDw3;
    const float4* sDb3_4 = (const float4*)sDb3;
    const float4* sGm_4  = (const float4*)sGm;
    const float4* sEw2_4 = (const float4*)sEw2;
    const float4* sDw2_4 = (const float4*)sDw2;
    const float4* sTw1_4 = (const float4*)sTw1;
    const float4* sTw2_4 = (const float4*)sTw2;

    float u[16], v[16];
#pragma unroll
    for (int k = 0; k < 16; ++k) { u[k] = 0.f; v[k] = 0.f; }
    float s2 = 0.f, sb = 0.f;

    auto consume = [&](int blk, int bofs) {
        float xe[16];
#pragma unroll
        for (int q = 0; q < 4; ++q) {
            float4 w4 = lbuf[bofs + t * 4 + (q ^ sw2)];
            xe[q * 4 + 0] = w4.x; xe[q * 4 + 1] = w4.y;
            xe[q * 4 + 2] = w4.z; xe[q * 4 + 3] = w4.w;
        }
        int j0 = blk * 16;
        // s2 / sb (same accumulation order as before: e ascending)
#pragma unroll
        for (int ee = 0; ee < 4; ++ee) {
            float4 bv = sDb3_4[(j0 >> 2) + ee];
            s2 = fmaf(xe[ee*4+0], xe[ee*4+0], s2); sb = fmaf(xe[ee*4+0], bv.x, sb);
            s2 = fmaf(xe[ee*4+1], xe[ee*4+1], s2); sb = fmaf(xe[ee*4+1], bv.y, sb);
            s2 = fmaf(xe[ee*4+2], xe[ee*4+2], s2); sb = fmaf(xe[ee*4+2], bv.z, sb);
            s2 = fmaf(xe[ee*4+3], xe[ee*4+3], s2); sb = fmaf(xe[ee*4+3], bv.w, sb);
        }
        // u: per e, read ew1 row (16 floats = 4xfloat4), 16 FMA
#pragma unroll
        for (int e = 0; e < 16; ++e) {
            float x = xe[e];
#pragma unroll
            for (int kk = 0; kk < 4; ++kk) {
                float4 wv = sEw1_4[(j0 + e) * 4 + kk];
                u[kk*4+0] = fmaf(x, wv.x, u[kk*4+0]);
                u[kk*4+1] = fmaf(x, wv.y, u[kk*4+1]);
                u[kk*4+2] = fmaf(x, wv.z, u[kk*4+2]);
                u[kk*4+3] = fmaf(x, wv.w, u[kk*4+3]);
            }
        }
        // v: per q, read dw3 row-segment (16 floats), 16 FMA (e ascending)
#pragma unroll
        for (int q = 0; q < 16; ++q) {
            float a2 = v[q];
#pragma unroll
            for (int ee = 0; ee < 4; ++ee) {
                float4 wv = sDw3_4[q * 32 + (j0 >> 2) + ee];
                a2 = fmaf(xe[ee*4+0], wv.x, a2);
                a2 = fmaf(xe[ee*4+1], wv.y, a2);
                a2 = fmaf(xe[ee*4+2], wv.z, a2);
                a2 = fmaf(xe[ee*4+3], wv.w, a2);
            }
            v[q] = a2;
        }
    };

#pragma unroll 1
    for (int blk = 0; blk < 7; ++blk) {
        int nb = ((blk + 1) & 1) * 1024;
#pragma unroll
        for (int c2 = 0; c2 < 4; ++c2) {
            __builtin_amdgcn_global_load_lds(
                (const __attribute__((address_space(1))) void*)p[c2],
                (__attribute__((address_space(3))) void*)(lbuf + nb + (w * 4 + c2) * 64),
                16, 0, 0);
            p[c2] += 4;
        }
        asm volatile("s_waitcnt vmcnt(4)" ::: "memory");
        __builtin_amdgcn_sched_barrier(0);
        consume(blk, (blk & 1) * 1024);
    }
    asm volatile("s_waitcnt vmcnt(0)" ::: "memory");
    __builtin_amdgcn_sched_barrier(0);
    consume(7, 1024);

    // encoder tail (weights from LDS)
    float h1[16];
#pragma unroll
    for (int k = 0; k < 16; ++k) h1[k] = ftanh(u[k] + sEb1[k]);
    float a2m[8];
#pragma unroll
    for (int m = 0; m < 8; ++m) a2m[m] = sEb2[m];
#pragma unroll
    for (int k = 0; k < 16; ++k) {
        float4 r0 = sEw2_4[k * 2], r1 = sEw2_4[k * 2 + 1];
        a2m[0] = fmaf(h1[k], r0.x, a2m[0]); a2m[1] = fmaf(h1[k], r0.y, a2m[1]);
        a2m[2] = fmaf(h1[k], r0.z, a2m[2]); a2m[3] = fmaf(h1[k], r0.w, a2m[3]);
        a2m[4] = fmaf(h1[k], r1.x, a2m[4]); a2m[5] = fmaf(h1[k], r1.y, a2m[5]);
        a2m[6] = fmaf(h1[k], r1.z, a2m[6]); a2m[7] = fmaf(h1[k], r1.w, a2m[7]);
    }
    float h2[8];
#pragma unroll
    for (int m = 0; m < 8; ++m) h2[m] = ftanh(a2m[m]);
    float a3 = sEb3;
#pragma unroll
    for (int m = 0; m < 8; ++m) a3 = fmaf(h2[m], sEw3[m], a3);
    float z1 = ftanh(a3);

    // decoder
    float d1[8];
#pragma unroll
    for (int p2 = 0; p2 < 8; ++p2) d1[p2] = ftanh(fmaf(z1, sDw1[p2], sDb1[p2]));
    float a2q[16];
#pragma unroll
    for (int q = 0; q < 16; ++q) a2q[q] = sDb2[q];
#pragma unroll
    for (int p2 = 0; p2 < 8; ++p2) {
#pragma unroll
        for (int q4 = 0; q4 < 4; ++q4) {
            float4 r = sDw2_4[p2 * 4 + q4];
            a2q[q4*4+0] = fmaf(d1[p2], r.x, a2q[q4*4+0]);
            a2q[q4*4+1] = fmaf(d1[p2], r.y, a2q[q4*4+1]);
            a2q[q4*4+2] = fmaf(d1[p2], r.z, a2q[q4*4+2]);
            a2q[q4*4+3] = fmaf(d1[p2], r.w, a2q[q4*4+3]);
        }
    }
    float d2[16];
#pragma unroll
    for (int q = 0; q < 16; ++q) d2[q] = ftanh(a2q[q]);

    // distances via LDS-resident Gram
    float dot = sb;
#pragma unroll
    for (int q = 0; q < 16; ++q) dot = fmaf(d2[q], v[q], dot);
    float n2 = sBb;
#pragma unroll
    for (int a = 0; a < 16; ++a) {
        float ra = 2.0f * sGv[a];
#pragma unroll
        for (int b4 = 0; b4 < 4; ++b4) {
            float4 g = sGm_4[a * 4 + b4];
            ra = fmaf(g.x, d2[b4*4+0], ra);
            ra = fmaf(g.y, d2[b4*4+1], ra);
            ra = fmaf(g.z, d2[b4*4+2], ra);
            ra = fmaf(g.w, d2[b4*4+3], ra);
        }
        n2 = fmaf(d2[a], ra, n2);
    }
    n2 = fmaxf(n2, 1e-20f);
    float euc2 = fmaxf(s2 - 2.0f * dot + n2, 0.f);
    float deuc = sqrtf(euc2);
    float dcos = dot * rsqrtf(s2 * n2);

    float zf[3] = {z1, dcos, deuc};

    // estimator
    float e1a[8];
#pragma unroll
    for (int p2 = 0; p2 < 8; ++p2) e1a[p2] = sTb1[p2];
#pragma unroll
    for (int d = 0; d < 3; ++d) {
        float4 r0 = sTw1_4[d * 2], r1 = sTw1_4[d * 2 + 1];
        e1a[0] = fmaf(zf[d], r0.x, e1a[0]); e1a[1] = fmaf(zf[d], r0.y, e1a[1]);
        e1a[2] = fmaf(zf[d], r0.z, e1a[2]); e1a[3] = fmaf(zf[d], r0.w, e1a[3]);
        e1a[4] = fmaf(zf[d], r1.x, e1a[4]); e1a[5] = fmaf(zf[d], r1.y, e1a[5]);
        e1a[6] = fmaf(zf[d], r1.z, e1a[6]); e1a[7] = fmaf(zf[d], r1.w, e1a[7]);
    }
    float e1[8];
#pragma unroll
    for (int p2 = 0; p2 < 8; ++p2) e1[p2] = ftanh(e1a[p2]);
    float lg[4];
#pragma unroll
    for (int k = 0; k < 4; ++k) lg[k] = sTb2[k];
#pragma unroll
    for (int p2 = 0; p2 < 8; ++p2) {
        float4 r = sTw2_4[p2];
        lg[0] = fmaf(e1[p2], r.x, lg[0]); lg[1] = fmaf(e1[p2], r.y, lg[1]);
        lg[2] = fmaf(e1[p2], r.z, lg[2]); lg[3] = fmaf(e1[p2], r.w, lg[3]);
    }
    float mx = fmaxf(fmaxf(lg[0], lg[1]), fmaxf(lg[2], lg[3]));
    float ex[4]; float se = 0.f;
#pragma unroll
    for (int k = 0; k < 4; ++k) { ex[k] = __expf(lg[k] - mx); se += ex[k]; }
    float inv = __fdividef(1.0f, se);
    float gam[4];
#pragma unroll
    for (int k = 0; k < 4; ++k) gam[k] = ex[k] * inv;

    if (active) zbuf[i] = make_float4(zf[0], zf[1], zf[2], 0.f);
    if (!active) { gam[0] = gam[1] = gam[2] = gam[3] = 0.f; euc2 = 0.f; }

    // block reduction of 41 moment values
    int rlane = threadIdx.x & 63;
    int wid = threadIdx.x >> 6;

#define REDUCE_STORE(T, VAL) { float _v = (VAL);                          \
        _v += __shfl_down(_v, 32); _v += __shfl_down(_v, 16);             \
        _v += __shfl_down(_v, 8);  _v += __shfl_down(_v, 4);              \
        _v += __shfl_down(_v, 2);  _v += __shfl_down(_v, 1);              \
        if (rlane == 0) sPart[wid][T] = _v; }

#pragma unroll
    for (int k = 0; k < 4; ++k) REDUCE_STORE(k, gam[k]);
#pragma unroll
    for (int k = 0; k < 4; ++k) {
#pragma unroll
        for (int d = 0; d < 3; ++d) REDUCE_STORE(4 + k * 3 + d, gam[k] * zf[d]);
    }
#pragma unroll
    for (int k = 0; k < 4; ++k) {
        REDUCE_STORE(16 + k * 6 + 0, gam[k] * zf[0] * zf[0]);
        REDUCE_STORE(16 + k * 6 + 1, gam[k] * zf[0] * zf[1]);
        REDUCE_STORE(16 + k * 6 + 2, gam[k] * zf[0] * zf[2]);
        REDUCE_STORE(16 + k * 6 + 3, gam[k] * zf[1] * zf[1]);
        REDUCE_STORE(16 + k * 6 + 4, gam[k] * zf[1] * zf[2]);
        REDUCE_STORE(16 + k * 6 + 5, gam[k] * zf[2] * zf[2]);
    }
    REDUCE_STORE(40, euc2);
#undef REDUCE_STORE

    __syncthreads();
    if (threadIdx.x < 41) {
        double s = (double)sPart[0][threadIdx.x] + (double)sPart[1][threadIdx.x]
                 + (double)sPart[2][threadIdx.x] + (double)sPart[3][threadIdx.x];
        double* accs = acc + (size_t)(blockIdx.x & 7) * 48;   // contention spread
        unsafeAtomicAdd(&accs[threadIdx.x], s);
    }
}

__global__ void gmm_kernel(double* __restrict__ acc, float* __restrict__ P) {
    if (threadIdx.x != 0 || blockIdx.x != 0) return;
    // consolidate the 8 contention-spread copies into copy 0
    for (int j = 0; j < 42; ++j) {
        double s = acc[j];
        for (int c = 1; c < 8; ++c) s += acc[c * 48 + j];
        acc[j] = s;
    }
    double M[6] = {0, 0, 0, 0, 0, 0}, bv[3] = {0, 0, 0}, A = 0.0, loss3 = 0.0;
    const double TWO_PI = 6.283185307179586;
    for (int k = 0; k < 4; ++k) {
        double g = acc[k];
        double phi = g / (double)NSAMP;
        double mu0 = acc[4 + k * 3 + 0] / g;
        double mu1 = acc[4 + k * 3 + 1] / g;
        double mu2 = acc[4 + k * 3 + 2] / g;
        double S00 = acc[16 + k * 6 + 0] / g - mu0 * mu0;
        double S01 = acc[16 + k * 6 + 1] / g - mu0 * mu1;
        double S02 = acc[16 + k * 6 + 2] / g - mu0 * mu2;
        double S11 = acc[16 + k * 6 + 3] / g - mu1 * mu1;
        double S12 = acc[16 + k * 6 + 4] / g - mu1 * mu2;
        double S22 = acc[16 + k * 6 + 5] / g - mu2 * mu2;
        double c00 = S11 * S22 - S12 * S12;
        double c01 = S02 * S12 - S01 * S22;
        double c02 = S01 * S12 - S02 * S11;
        double det = S00 * c00 + S01 * c01 + S02 * c02;
        double id = 1.0 / det;
        double I00 = c00 * id, I01 = c01 * id, I02 = c02 * id;
        double I11 = (S00 * S22 - S02 * S02) * id;
        double I12 = (S01 * S02 - S00 * S12) * id;
        double I22 = (S00 * S11 - S01 * S01) * id;
        M[0] += I00; M[1] += I01; M[2] += I02; M[3] += I11; M[4] += I12; M[5] += I22;
        double b0 = I00 * mu0 + I01 * mu1 + I02 * mu2;
        double b1 = I01 * mu0 + I11 * mu1 + I12 * mu2;
        double b2 = I02 * mu0 + I12 * mu1 + I22 * mu2;
        bv[0] += b0; bv[1] += b1; bv[2] += b2;
        double quad = mu0 * b0 + mu1 * b1 + mu2 * b2;
        A += -log(phi) + 0.5 * log(TWO_PI * TWO_PI * TWO_PI * det) + 0.5 * quad;
        loss3 += 1e-4 * (1.0 / S00 + 1.0 / S11 + 1.0 / S22);
    }
    P[0] = (float)M[0]; P[1] = (float)M[1]; P[2] = (float)M[2];
    P[3] = (float)M[3]; P[4] = (float)M[4]; P[5] = (float)M[5];
    P[6] = (float)bv[0]; P[7] = (float)bv[1]; P[8] = (float)bv[2];
    P[9] = (float)A;
    acc[42] = acc[40] / (double)NSAMP + loss3;   // loss1 + loss3
}

__global__ __launch_bounds__(256) void energy_kernel(const float4* __restrict__ zbuf,
                                                     const float* __restrict__ P,
                                                     double* __restrict__ acc,
                                                     unsigned* __restrict__ cnt,
                                                     float* __restrict__ out) {
    int i = blockIdx.x * 256 + threadIdx.x;
    float e = 0.f;
    if (i < NSAMP) {
        float4 z4 = zbuf[i];
        float z0 = z4.x, z1 = z4.y, z2 = z4.z;
        float q = P[0] * z0 * z0 + P[3] * z1 * z1 + P[5] * z2 * z2
                + 2.f * (P[1] * z0 * z1 + P[2] * z0 * z2 + P[4] * z1 * z2);
        e = P[9] + 0.5f * q - (P[6] * z0 + P[7] * z1 + P[8] * z2);
        out[i] = e;
    }
    float s = e;
    s += __shfl_down(s, 32); s += __shfl_down(s, 16); s += __shfl_down(s, 8);
    s += __shfl_down(s, 4);  s += __shfl_down(s, 2);  s += __shfl_down(s, 1);
    __shared__ float sE[4];
    if ((threadIdx.x & 63) == 0) sE[threadIdx.x >> 6] = s;
    __syncthreads();
    if (threadIdx.x == 0) {
        double t = (double)sE[0] + (double)sE[1] + (double)sE[2] + (double)sE[3];
        double* accs = acc + (size_t)(blockIdx.x & 7) * 48;
        unsafeAtomicAdd(&accs[41], t);
        __threadfence();
        unsigned old = atomicAdd(cnt, 1u);
        if (old == (unsigned)(NBLK - 1)) {
            double tot = 0.0;
            for (int c = 0; c < 8; ++c)
                tot += unsafeAtomicAdd(&acc[c * 48 + 41], 0.0);  // coherent read
            out[NSAMP] = (float)(acc[42] + 0.01 * tot / (double)NSAMP);
        }
    }
}

extern "C" void kernel_launch(void* const* d_in, const int* in_sizes, int n_in,
                              void* d_out, int out_size, void* d_ws, size_t ws_size,
                              hipStream_t stream) {
    const float* x1  = (const float*)d_in[0];
    const float* ew1 = (const float*)d_in[1];
    const float* eb1 = (const float*)d_in[2];
    const float* ew2 = (const float*)d_in[3];
    const float* eb2 = (const float*)d_in[4];
    const float* ew3 = (const float*)d_in[5];
    const float* eb3 = (const float*)d_in[6];
    const float* dw1 = (const float*)d_in[7];
    const float* db1 = (const float*)d_in[8];
    const float* dw2 = (const float*)d_in[9];
    const float* db2 = (const float*)d_in[10];
    const float* dw3 = (const float*)d_in[11];
    const float* db3 = (const float*)d_in[12];
    const float* tw1 = (const float*)d_in[13];
    const float* tb1 = (const float*)d_in[14];
    const float* tw2 = (const float*)d_in[15];
    const float* tb2 = (const float*)d_in[16];
    float* out = (float*)d_out;
    char* ws = (char*)d_ws;
    double* acc   = (double*)ws;                 // 8 copies x 48 doubles
    unsigned* cnt = (unsigned*)(ws + 3072);
    float* P    = (float*)(ws + 3584);
    float* Gm   = (float*)(ws + 4096);
    float* gv   = (float*)(ws + 5120);
    float* bb   = (float*)(ws + 5184);
    float4* zb  = (float4*)(ws + 8192);

    hipMemsetAsync(d_ws, 0, 3584, stream);
    prep_kernel<<<1, 256, 0, stream>>>(dw3, db3, Gm, gv, bb);
    pass1_kernel<<<NBLK, 256, 0, stream>>>(x1, ew1, eb1, ew2, eb2, ew3, eb3,
                                           dw1, db1, dw2, db2, dw3, db3,
                                           tw1, tb1, tw2, tb2, Gm, gv, bb, acc, zb);
    gmm_kernel<<<1, 64, 0, stream>>>(acc, P);
    energy_kernel<<<NBLK, 256, 0, stream>>>(zb, P, acc, cnt, out);
}